// Round 2
// baseline (111.530 us; speedup 1.0000x reference)
//
#include <hip/hip_runtime.h>
#include <math.h>

#define Bq 8
#define Nq 325
#define F_INq 32
#define Tq 24
#define HCq 128
#define KMAX 4
#define NBN 109  // ceil(325/3) neighbor-extract blocks, 3 nodes/block (1 per wave)

// ---- K1: blocks 0..108: neighbor extract, 3 nodes per block (one per wave);
//      block 109: packs; blocks 110..213: xpart partial sums over 25-node chunks ----
__global__ __launch_bounds__(192) void prep_kernel(
    const float* __restrict__ iw, const float* __restrict__ ib,
    const float* __restrict__ adj, const float* __restrict__ Ww,
    const float* __restrict__ Wb, const float* __restrict__ attnw,
    const float* __restrict__ x,
    int* __restrict__ nbr_cnt, int* __restrict__ nbr_idx, float* __restrict__ nbr_w,
    float* __restrict__ Wp, float* __restrict__ bx, float* __restrict__ xp) {
  int blk = blockIdx.x;
  int tid = threadIdx.x;
  if (blk < NBN) {
    int lane = tid & 63;
    int i = blk * 3 + (tid >> 6);        // wave w -> node 3*blk+w; no barriers here
    if (i >= Nq) return;
    const float* iwr = iw + (size_t)i * Nq;
    const float* ibr = ib + (size_t)i * Nq;
    const float* ar  = adj + (size_t)i * Nq;
    float wa_c[6], a_c[6];
    float sum = 0.f;
    #pragma unroll
    for (int c = 0; c < 6; ++c) {
      int j = c * 64 + lane;
      float wa = 0.f, a = 0.f;
      if (j < Nq) {
        float basev = ibr[j];
        float w = iwr[j];
        w = fminf(fmaxf(w, basev * 0.5f), basev * 1.5f);
        w = fmaxf(w, 0.f);
        a = ar[j];
        wa = w * a;
      }
      wa_c[c] = wa; a_c[c] = a;
      sum += wa;
    }
    #pragma unroll
    for (int off = 32; off >= 1; off >>= 1) sum += __shfl_xor(sum, off, 64);
    if (sum == 0.f) sum = 1e-6f;
    float inv = 1.f / sum;
    unsigned long long below = (1ull << lane) - 1ull;
    int base = 0;
    #pragma unroll
    for (int c = 0; c < 6; ++c) {
      int j = c * 64 + lane;
      bool pred = (j < Nq) && (a_c[c] != 0.f);
      unsigned long long m = __ballot(pred);
      int rank = base + __popcll(m & below);
      if (pred && rank < KMAX) {
        nbr_idx[i * KMAX + rank] = j;
        nbr_w[i * KMAX + rank]   = wa_c[c] * inv;
      }
      base += __popcll(m);
    }
    if (lane == 0) {
      int cnt = base < KMAX ? base : KMAX;
      for (int k = cnt; k < KMAX; ++k) { nbr_idx[i * KMAX + k] = 0; nbr_w[i * KMAX + k] = 0.f; }
      nbr_cnt[i] = cnt;
    }
    return;
  }
  if (blk == NBN) {
    // Wp[p][f]: p=0..3 a1-projected row per head; p=4..7 a2-projected
    for (int o = tid; o < 8 * F_INq; o += 192) {
      int p = o >> 5, f = o & 31;
      int h = p & 3, c0 = (p < 4) ? 0 : 32;
      float v = 0.f;
      for (int c = 0; c < 32; ++c)
        v += Ww[(h * 32 + c) * F_INq + f] * attnw[h * 64 + c0 + c];
      Wp[o] = v;
    }
    // bx[0..127]=Wb; bx[128+h]=a1-proj bias; bx[132+h]=a2-proj bias
    for (int r = tid; r < 136; r += 192) {
      float v;
      if (r < HCq) {
        v = Wb[r];
      } else {
        int h = (r - HCq) & 3, c0 = (r < 132) ? 0 : 32;
        v = 0.f;
        for (int c = 0; c < 32; ++c) v += Wb[h * 32 + c] * attnw[h * 64 + c0 + c];
      }
      bx[r] = v;
    }
    return;
  }
  // xpart: partial sums of x over 25-node chunks
  {
    int pblk = blk - (NBN + 1);           // 0..103 = b*13 + c
    int b = pblk / 13, c = pblk - b * 13;
    const float4* src = (const float4*)x + ((size_t)b * Nq + c * 25) * 192;
    float4 a = {0.f, 0.f, 0.f, 0.f};
    #pragma unroll 5
    for (int n = 0; n < 25; ++n) {
      float4 v = src[(size_t)n * 192 + tid];
      a.x += v.x; a.y += v.y; a.z += v.z; a.w += v.w;
    }
    ((float4*)xp)[(size_t)pblk * 192 + tid] = a;
  }
}

// ---- K2: fused tables -> yv precompute -> full-lane GEMM -> direct stores --------
// Block = 2 nodes (i0, i0+1) of one b. GEMM: wave w = head h; lane = (ii, c).
__global__ __launch_bounds__(256) void fused_kernel(
    const float* __restrict__ x, const float* __restrict__ Wp,
    const float* __restrict__ Ww, const float* __restrict__ bx,
    const float* __restrict__ xp,
    const int* __restrict__ nbr_cnt, const int* __restrict__ nbr_idx,
    const float* __restrict__ nbr_w, float* __restrict__ out) {
  __shared__ __align__(16) float sx[6144];          // [ii][slot][f*24+t]
  __shared__ __align__(16) float sxs[768];          // xs[b][f*24+t]
  __shared__ __align__(16) float syv[6144];         // yv[ii][h][f][t]
  __shared__ __align__(16) float sinit[192];        // initc[ii][h][t]
  __shared__ float ssw[2][3];
  __shared__ int ssi[2][3], scnt2[2];
  int tid = threadIdx.x;
  int blk = blockIdx.x;
  int b = blk / 163;
  int i0 = (blk - b * 163) * 2;
  int valid1 = (i0 + 1 < Nq) ? 1 : 0;

  // GEMM identity + weight preload (independent of everything; issue early)
  int lane = tid & 63;
  int h = tid >> 6;                        // wave id = head
  int gii = lane >> 5, c = lane & 31;
  int r = h * 32 + c;
  float wr_[32];
  {
    const float4* wwp = (const float4*)(Ww + r * 32);   // native [r][f] layout
    #pragma unroll
    for (int q = 0; q < 8; ++q) {
      float4 v = wwp[q];
      wr_[4 * q] = v.x; wr_[4 * q + 1] = v.y; wr_[4 * q + 2] = v.z; wr_[4 * q + 3] = v.w;
    }
  }
  float bxv = bx[r];

  if (tid < 2) {
    int i = i0 + (tid & valid1);
    int cc = nbr_cnt[i];
    scnt2[tid] = cc < 3 ? cc : 3;
  }
  if (tid < 6) {
    int ii = tid / 3, k = tid - ii * 3;
    int i = i0 + (ii & valid1);
    ssi[ii][k] = nbr_idx[i * KMAX + k];
    ssw[ii][k] = nbr_w[i * KMAX + k];
  }
  __syncthreads();
  // stage x tiles (8 slots, coalesced float4) + xs reduction from 13 partials
  const float4* x4 = (const float4*)x;
  float4* sx4 = (float4*)sx;
  #pragma unroll
  for (int j = 0; j < 6; ++j) {
    int idx = tid + j * 256;              // [0,1536)
    int slot = idx / 192, e4 = idx - slot * 192;
    int ii = slot >> 2, sl = slot & 3;
    int node = (sl == 0) ? (i0 + (ii & valid1)) : ssi[ii][sl - 1];
    sx4[idx] = x4[((size_t)(b * Nq + node)) * 192 + e4];
  }
  if (tid < 192) {
    const float4* xpb = (const float4*)xp + (size_t)b * 13 * 192;
    float4 a = {0.f, 0.f, 0.f, 0.f};
    #pragma unroll
    for (int cc = 0; cc < 13; ++cc) {
      float4 v = xpb[cc * 192 + tid];
      a.x += v.x; a.y += v.y; a.z += v.z; a.w += v.w;
    }
    ((float4*)sxs)[tid] = a;
  }
  __syncthreads();
  // tables: f1(self)+f2(nbrs) -> sparse-softmax -> initc + yv into LDS
  if (tid < 192) {
    int ii = tid / 96, r96 = tid - ii * 96;
    int th = r96 / 24, t = r96 - th * 24;
    const float* xi  = sx + (ii * 4 + 0) * 768 + t;
    const float* xj0 = sx + (ii * 4 + 1) * 768 + t;
    const float* xj1 = sx + (ii * 4 + 2) * 768 + t;
    const float* xj2 = sx + (ii * 4 + 3) * 768 + t;
    const float* w1 = Wp + th * 32;
    const float* w2 = Wp + (4 + th) * 32;
    float f1 = bx[128 + th], g0 = bx[132 + th], g1 = g0, g2 = g0;
    #pragma unroll
    for (int f = 0; f < 32; ++f) {
      float wa = w1[f], wb2 = w2[f];
      f1 += wa * xi[f * 24];
      g0 += wb2 * xj0[f * 24];
      g1 += wb2 * xj1[f * 24];
      g2 += wb2 * xj2[f * 24];
    }
    int cnt = scnt2[ii];
    float fv[3] = {g0, g1, g2};
    float sv[3];
    float m = 0.f;                        // >= N-cnt exact-zero score entries
    #pragma unroll
    for (int k = 0; k < 3; ++k) {
      float s = 0.f;
      if (k < cnt) {
        float e = f1 + fv[k];
        e = e > 0.f ? e : 0.2f * e;       // leaky_relu 0.2
        s = e + ssw[ii][k];
        m = fmaxf(m, s);
      }
      sv[k] = s;
    }
    float em = __expf(-m);
    float Z = (float)(Nq - cnt) * em;
    float pk[3];
    #pragma unroll
    for (int k = 0; k < 3; ++k) {
      float p = 0.f;
      if (k < cnt) { p = __expf(sv[k] - m); Z += p; }
      pk[k] = p;
    }
    float invZ = 1.f / Z;
    float bp = em * invZ;
    float pd0 = (0 < cnt) ? pk[0] * invZ - bp : 0.f;
    float pd1 = (1 < cnt) ? pk[1] * invZ - bp : 0.f;
    float pd2 = (2 < cnt) ? pk[2] * invZ - bp : 0.f;
    float ps = pd0 + pd1 + pd2;
    sinit[(ii * 4 + th) * 24 + t] = ps + 325.f * bp;
    // yv[ii][th][f][t] = pd0*xj0 + pd1*xj1 + pd2*xj2 + bp*xs
    float* yvw = syv + (ii * 4 + th) * 768 + t;
    const float* xsp = sxs + t;
    #pragma unroll
    for (int f = 0; f < 32; ++f) {
      yvw[f * 24] = pd0 * xj0[f * 24] + pd1 * xj1[f * 24] + pd2 * xj2[f * 24]
                  + bp * xsp[f * 24];
    }
  }
  __syncthreads();
  // full-lane GEMM: acc[t] = initc*bx[r] + sum_f wr[f]*yv[ii][h][f][t]
  float acc[24];
  {
    const float* sip = sinit + (gii * 4 + h) * 24;
    #pragma unroll
    for (int t = 0; t < 24; ++t) acc[t] = sip[t] * bxv;
    const float* yvp = syv + (gii * 4 + h) * 768;
    #pragma unroll 4
    for (int f = 0; f < 32; ++f) {
      const float* yf = yvp + f * 24;
      float wv = wr_[f];
      #pragma unroll
      for (int t = 0; t < 24; ++t) acc[t] += wv * yf[t];
    }
  }
  // direct coalesced stores: lane owns out[b][node][r][0..23] (24 contiguous floats)
  int node = i0 + gii;
  if (node < Nq) {
    float4* op4 = (float4*)(out + ((size_t)(b * Nq + node) * HCq + r) * Tq);
    #pragma unroll
    for (int q = 0; q < 6; ++q) {
      float4 v;
      v.x = acc[4 * q]; v.y = acc[4 * q + 1]; v.z = acc[4 * q + 2]; v.w = acc[4 * q + 3];
      op4[q] = v;
    }
  }
}

extern "C" void kernel_launch(void* const* d_in, const int* in_sizes, int n_in,
                              void* d_out, int out_size, void* d_ws, size_t ws_size,
                              hipStream_t stream) {
  const float* x     = (const float*)d_in[0];
  const float* Ww    = (const float*)d_in[1];
  const float* Wb    = (const float*)d_in[2];
  const float* attnw = (const float*)d_in[3];
  const float* iw    = (const float*)d_in[4];
  const float* ib    = (const float*)d_in[5];
  const float* adj   = (const float*)d_in[6];
  float* out = (float*)d_out;

  float* ws = (float*)d_ws;
  float* xp  = ws;                         // 8*13*768 = 79,872
  float* Wp  = xp + (size_t)Bq * 13 * 768; // 256
  float* bx  = Wp + 8 * F_INq;             // 136
  int* nbr_cnt = (int*)(bx + 136);
  int* nbr_idx = nbr_cnt + Nq;
  float* nbr_w = (float*)(nbr_idx + Nq * KMAX);

  prep_kernel<<<NBN + 1 + Bq * 13, 192, 0, stream>>>(
      iw, ib, adj, Ww, Wb, attnw, x,
      nbr_cnt, nbr_idx, nbr_w, Wp, bx, xp);
  fused_kernel<<<Bq * 163, 256, 0, stream>>>(x, Wp, Ww, bx, xp,
                                             nbr_cnt, nbr_idx, nbr_w, out);
}

// Round 3
// 104.075 us; speedup vs baseline: 1.0716x; 1.0716x over previous
//
#include <hip/hip_runtime.h>
#include <math.h>

#define Bq 8
#define Nq 325
#define F_INq 32
#define Tq 24
#define HCq 128
#define KMAX 4

// ---- K1: blocks 0..324 neighbor extract (wave0, ballot rank); block 325: packs;
//      blocks 326..429: xpart partial sums over 25-node chunks --------------------
__global__ __launch_bounds__(192) void prep_kernel(
    const float* __restrict__ iw, const float* __restrict__ ib,
    const float* __restrict__ adj, const float* __restrict__ Ww,
    const float* __restrict__ Wb, const float* __restrict__ attnw,
    const float* __restrict__ x,
    int* __restrict__ nbr_cnt, int* __restrict__ nbr_idx, float* __restrict__ nbr_w,
    float* __restrict__ WxT, float* __restrict__ Wp,
    float* __restrict__ bx, float* __restrict__ xp) {
  int blk = blockIdx.x;
  int tid = threadIdx.x;
  if (blk < Nq) {
    if (tid >= 64) return;               // wave 0 only; no barriers in this path
    int lane = tid;
    int i = blk;
    const float* iwr = iw + (size_t)i * Nq;
    const float* ibr = ib + (size_t)i * Nq;
    const float* ar  = adj + (size_t)i * Nq;
    float wa_c[6], a_c[6];
    float sum = 0.f;
    #pragma unroll
    for (int c = 0; c < 6; ++c) {
      int j = c * 64 + lane;
      float wa = 0.f, a = 0.f;
      if (j < Nq) {
        float basev = ibr[j];
        float w = iwr[j];
        w = fminf(fmaxf(w, basev * 0.5f), basev * 1.5f);
        w = fmaxf(w, 0.f);
        a = ar[j];
        wa = w * a;
      }
      wa_c[c] = wa; a_c[c] = a;
      sum += wa;
    }
    #pragma unroll
    for (int off = 32; off >= 1; off >>= 1) sum += __shfl_xor(sum, off, 64);
    if (sum == 0.f) sum = 1e-6f;
    float inv = 1.f / sum;
    unsigned long long below = (1ull << lane) - 1ull;
    int base = 0;
    #pragma unroll
    for (int c = 0; c < 6; ++c) {
      int j = c * 64 + lane;
      bool pred = (j < Nq) && (a_c[c] != 0.f);
      unsigned long long m = __ballot(pred);
      int rank = base + __popcll(m & below);
      if (pred && rank < KMAX) {
        nbr_idx[i * KMAX + rank] = j;
        nbr_w[i * KMAX + rank]   = wa_c[c] * inv;
      }
      base += __popcll(m);
    }
    if (lane == 0) {
      int cnt = base < KMAX ? base : KMAX;
      for (int k = cnt; k < KMAX; ++k) { nbr_idx[i * KMAX + k] = 0; nbr_w[i * KMAX + k] = 0.f; }
      nbr_cnt[i] = cnt;
    }
    return;
  }
  if (blk == Nq) {
    // WxT[f][r] = Ww[r][f] for fused GEMM wave-uniform s_loads
    for (int o = tid; o < F_INq * HCq; o += 192) {
      int f = o >> 7, r = o & 127;
      WxT[o] = Ww[r * F_INq + f];
    }
    // Wp[p][f]: p=0..3 a1-projected row per head; p=4..7 a2-projected
    for (int o = tid; o < 8 * F_INq; o += 192) {
      int p = o >> 5, f = o & 31;
      int h = p & 3, c0 = (p < 4) ? 0 : 32;
      float v = 0.f;
      for (int c = 0; c < 32; ++c)
        v += Ww[(h * 32 + c) * F_INq + f] * attnw[h * 64 + c0 + c];
      Wp[o] = v;
    }
    // bx[0..127]=Wb; bx[128+h]=a1-proj bias; bx[132+h]=a2-proj bias
    for (int r = tid; r < 136; r += 192) {
      float v;
      if (r < HCq) {
        v = Wb[r];
      } else {
        int h = (r - HCq) & 3, c0 = (r < 132) ? 0 : 32;
        v = 0.f;
        for (int c = 0; c < 32; ++c) v += Wb[h * 32 + c] * attnw[h * 64 + c0 + c];
      }
      bx[r] = v;
    }
    return;
  }
  // xpart: partial sums of x over 25-node chunks
  {
    int pblk = blk - (Nq + 1);            // 0..103 = b*13 + c
    int b = pblk / 13, c = pblk - b * 13;
    const float4* src = (const float4*)x + ((size_t)b * Nq + c * 25) * 192;
    float4 a = {0.f, 0.f, 0.f, 0.f};
    #pragma unroll 5
    for (int n = 0; n < 25; ++n) {
      float4 v = src[(size_t)n * 192 + tid];
      a.x += v.x; a.y += v.y; a.z += v.z; a.w += v.w;
    }
    ((float4*)xp)[(size_t)pblk * 192 + tid] = a;
  }
}

// ---- K2: fused tables + GEMM with S folded in (bp*xs term) + coalesced store ------
// Block = 2 nodes (i0, i0+1) of one b. Wave w <-> head h=w (rows 32w..32w+31).
__global__ __launch_bounds__(256) void fused_kernel(
    const float* __restrict__ x, const float* __restrict__ Wp,
    const float* __restrict__ WxT, const float* __restrict__ bx,
    const float* __restrict__ xp,
    const int* __restrict__ nbr_cnt, const int* __restrict__ nbr_idx,
    const float* __restrict__ nbr_w, float* __restrict__ out) {
  __shared__ __align__(16) float sx[6144];          // [ii][slot][f*24+t]; reused as out tile
  __shared__ __align__(16) float sxs[768];          // xs[b][f*24+t]
  __shared__ __align__(16) float spd[2][3][96];     // pd_k[ii][k][h*24+t]
  __shared__ float sbp[2][96], sps[2][96];
  __shared__ float ssw[2][3];
  __shared__ int ssi[2][3], scnt2[2];
  int tid = threadIdx.x;
  int blk = blockIdx.x;
  int b = blk / 163;
  int i0 = (blk - b * 163) * 2;
  int valid1 = (i0 + 1 < Nq) ? 1 : 0;
  if (tid < 2) {
    int i = i0 + (tid & valid1);
    int c = nbr_cnt[i];
    scnt2[tid] = c < 3 ? c : 3;
  }
  if (tid < 6) {
    int ii = tid / 3, k = tid - ii * 3;
    int i = i0 + (ii & valid1);
    ssi[ii][k] = nbr_idx[i * KMAX + k];
    ssw[ii][k] = nbr_w[i * KMAX + k];
  }
  __syncthreads();
  // stage x tiles (8 slots, coalesced float4) + xs reduction from 13 partials
  const float4* x4 = (const float4*)x;
  float4* sx4 = (float4*)sx;
  #pragma unroll
  for (int j = 0; j < 6; ++j) {
    int idx = tid + j * 256;              // [0,1536)
    int slot = idx / 192, e4 = idx - slot * 192;
    int ii = slot >> 2, sl = slot & 3;
    int node = (sl == 0) ? (i0 + (ii & valid1)) : ssi[ii][sl - 1];
    sx4[idx] = x4[((size_t)(b * Nq + node)) * 192 + e4];
  }
  if (tid < 192) {
    const float4* xpb = (const float4*)xp + (size_t)b * 13 * 192;
    float4 a = {0.f, 0.f, 0.f, 0.f};
    #pragma unroll
    for (int c = 0; c < 13; ++c) {
      float4 v = xpb[c * 192 + tid];
      a.x += v.x; a.y += v.y; a.z += v.z; a.w += v.w;
    }
    ((float4*)sxs)[tid] = a;
  }
  __syncthreads();
  // tables: f1(self)+f2(nbrs) -> sparse-softmax factors per (ii,h,t)
  if (tid < 192) {
    int ii = tid / 96, r96 = tid - ii * 96;
    int h = r96 / 24, t = r96 - h * 24;
    const float* xi  = sx + (ii * 4 + 0) * 768 + t;
    const float* xj0 = sx + (ii * 4 + 1) * 768 + t;
    const float* xj1 = sx + (ii * 4 + 2) * 768 + t;
    const float* xj2 = sx + (ii * 4 + 3) * 768 + t;
    const float* w1 = Wp + h * 32;
    const float* w2 = Wp + (4 + h) * 32;
    float f1 = bx[128 + h], g0 = bx[132 + h], g1 = g0, g2 = g0;
    #pragma unroll
    for (int f = 0; f < 32; ++f) {
      float wa = w1[f], wb2 = w2[f];
      f1 += wa * xi[f * 24];
      g0 += wb2 * xj0[f * 24];
      g1 += wb2 * xj1[f * 24];
      g2 += wb2 * xj2[f * 24];
    }
    int cnt = scnt2[ii];
    float fv[3] = {g0, g1, g2};
    float sv[3];
    float m = 0.f;                        // >= N-cnt exact-zero score entries
    #pragma unroll
    for (int k = 0; k < 3; ++k) {
      float s = 0.f;
      if (k < cnt) {
        float e = f1 + fv[k];
        e = e > 0.f ? e : 0.2f * e;       // leaky_relu 0.2
        s = e + ssw[ii][k];
        m = fmaxf(m, s);
      }
      sv[k] = s;
    }
    float em = __expf(-m);
    float Z = (float)(Nq - cnt) * em;
    float pk[3];
    #pragma unroll
    for (int k = 0; k < 3; ++k) {
      float p = 0.f;
      if (k < cnt) { p = __expf(sv[k] - m); Z += p; }
      pk[k] = p;
    }
    float invZ = 1.f / Z;
    float bp = em * invZ;
    float ps = 0.f;
    sbp[ii][r96] = bp;
    #pragma unroll
    for (int k = 0; k < 3; ++k) {
      float pd = (k < cnt) ? pk[k] * invZ - bp : 0.f;
      spd[ii][k][r96] = pd;
      ps += pd;
    }
    sps[ii][r96] = ps;
  }
  __syncthreads();
  // GEMM with S folded: yv = p0*x1+p1*x2+p2*x3 + bp*xs; acc init = (ps+325*bp)*bx
  int lane = tid & 63;
  int w = __builtin_amdgcn_readfirstlane(tid >> 6);   // wave id = head (uniform)
  int ii = lane / 24, t = lane - ii * 24;
  bool act = (lane < 48);
  float acc[32];
  if (act) {
    int ht = w * 24 + t;
    float bpv = sbp[ii][ht];
    float psv = sps[ii][ht];
    float p0 = spd[ii][0][ht], p1 = spd[ii][1][ht], p2 = spd[ii][2][ht];
    float initc = psv + 325.f * bpv;
    const float* bxp = bx + w * 32;                   // uniform -> s_load
    #pragma unroll
    for (int r = 0; r < 32; ++r) acc[r] = initc * bxp[r];
    const float* xj0 = sx + (ii * 4 + 1) * 768 + t;
    const float* xj1 = sx + (ii * 4 + 2) * 768 + t;
    const float* xj2 = sx + (ii * 4 + 3) * 768 + t;
    const float* xsp = sxs + t;
    const float* wtp = WxT + w * 32;                  // uniform -> s_load
    #pragma unroll 4
    for (int f = 0; f < 32; ++f) {
      float yv = p0 * xj0[f * 24] + p1 * xj1[f * 24] + p2 * xj2[f * 24]
               + bpv * xsp[f * 24];
      const float* wr = wtp + f * 128;
      #pragma unroll
      for (int r = 0; r < 32; ++r) acc[r] += wr[r] * yv;
    }
  }
  __syncthreads();                        // all reads of sx done before overwrite
  if (act) {
    float* otp = sx + ii * 3072 + (w * 32) * 24 + t;
    #pragma unroll
    for (int r = 0; r < 32; ++r) otp[r * 24] = acc[r];
  }
  __syncthreads();
  // coalesced float4 store (skip second node on the tail block)
  float4* o4 = (float4*)(out + ((size_t)(b * Nq + i0)) * 3072);
  int lim = valid1 ? 1536 : 768;
  #pragma unroll
  for (int j = 0; j < 6; ++j) {
    int idx = tid + j * 256;
    if (idx < lim) o4[idx] = sx4[idx];
  }
}

extern "C" void kernel_launch(void* const* d_in, const int* in_sizes, int n_in,
                              void* d_out, int out_size, void* d_ws, size_t ws_size,
                              hipStream_t stream) {
  const float* x     = (const float*)d_in[0];
  const float* Ww    = (const float*)d_in[1];
  const float* Wb    = (const float*)d_in[2];
  const float* attnw = (const float*)d_in[3];
  const float* iw    = (const float*)d_in[4];
  const float* ib    = (const float*)d_in[5];
  const float* adj   = (const float*)d_in[6];
  float* out = (float*)d_out;

  float* ws = (float*)d_ws;
  float* xp  = ws;                         // 8*13*768 = 79,872
  float* WxT = xp + (size_t)Bq * 13 * 768; // 4,096
  float* Wp  = WxT + F_INq * HCq;          // 256
  float* bx  = Wp + 8 * F_INq;             // 136
  int* nbr_cnt = (int*)(bx + 136);
  int* nbr_idx = nbr_cnt + Nq;
  float* nbr_w = (float*)(nbr_idx + Nq * KMAX);

  prep_kernel<<<Nq + 1 + Bq * 13, 192, 0, stream>>>(
      iw, ib, adj, Ww, Wb, attnw, x,
      nbr_cnt, nbr_idx, nbr_w, WxT, Wp, bx, xp);
  fused_kernel<<<Bq * 163, 256, 0, stream>>>(x, Wp, WxT, bx, xp,
                                             nbr_cnt, nbr_idx, nbr_w, out);
}